// Round 3
// baseline (297.835 us; speedup 1.0000x reference)
//
#include <hip/hip_runtime.h>
#include <cstdint>

// Problem constants (from the reference)
#define LL    200
#define QQ    21
#define MM    1024
#define START 133        // 2*L//3
#define NS    67         // L - START
#define RGH   0.01f
#define RGJ   0.01f

// ws layout:
//   [0,256)               : acc[0]=sum(J^2), acc[1]=sum(J*fij), acc[2]=sum w*logZ
//   [256, +NS*QQ*MM*4)    : logits slab, layout [iIdx][a][n]
//   [.., +LL*MM*4)        : tokT (transposed tokens, [j][n])
#define LOGITS_OFF 256
#define LOGITS_BYTES ((size_t)NS * QQ * MM * 4)
#define TOKT_OFF (LOGITS_OFF + LOGITS_BYTES)
#define WS_NEED (TOKT_OFF + (size_t)LL * MM * 4)

// LDS row stride 22 floats (88 B): bank-start = 22r mod 32, gcd(22,32)=2 ->
// 16 distinct starts -> max 2-way aliasing (free, m136). 88 % 8 == 0 -> every
// row is 8B-aligned -> ds_read_b64 legal. (16B alignment abandoned on purpose:
// LDS is bank-bound, b128 has no throughput edge and forces 8-start aliasing.)
#define RSTRIDE 22
#define TJ 16                        // j-tile
#define LDSJ_FLOATS (TJ * QQ * RSTRIDE)   // 7392 floats = 29568 B -> 4 blocks/CU

__device__ __forceinline__ float block_reduce_sum(float v) {
  // blockDim.x == 256 (4 waves) assumed
  __shared__ float sm[4];
  #pragma unroll
  for (int off = 32; off > 0; off >>= 1) v += __shfl_down(v, off, 64);
  const int lane = threadIdx.x & 63;
  const int wv   = threadIdx.x >> 6;
  __syncthreads();
  if (lane == 0) sm[wv] = v;
  __syncthreads();
  float r = 0.0f;
  if (threadIdx.x == 0) r = sm[0] + sm[1] + sm[2] + sm[3];
  return r;  // valid in thread 0 only
}

// ---------------------------------------------------------------------------
// Kernel A: sum(J^2) over all of J, and sum(J*fij) over {i>=START, j<i}.
// Grid (LL, QQ): block = one (i,a) row of 4200 floats. The j<i mask is the
// contiguous prefix pos < i*21 — block-uniform, no per-element division.
// ---------------------------------------------------------------------------
__global__ __launch_bounds__(256) void kern_jsum(
    const float* __restrict__ J, const float* __restrict__ fij,
    float* __restrict__ acc) {
  const int i = blockIdx.x;
  const int a = blockIdx.y;
  const size_t rb = (size_t)i * (QQ * LL * QQ) + (size_t)a * (LL * QQ);
  const float4* __restrict__ J4 = (const float4*)(J + rb);
  const float4* __restrict__ F4 = (const float4*)(fij + rb);
  const bool act = (i >= START);
  const int lim  = act ? i * QQ : 0;   // floats with j<i
  const int lim4 = lim >> 2;           // full float4s in the prefix
  const int rem  = lim & 3;
  float j2 = 0.0f, e = 0.0f;
  for (int f = threadIdx.x; f < (LL * QQ / 4); f += 256) {
    const float4 v = J4[f];
    j2 += v.x * v.x + v.y * v.y + v.z * v.z + v.w * v.w;
    if (f < lim4) {
      const float4 u = F4[f];
      e += v.x * u.x + v.y * u.y + v.z * u.z + v.w * u.w;
    } else if (f == lim4 && rem) {
      const float* vf = (const float*)&v;
      const float* uf = (const float*)(F4 + f);
      for (int k = 0; k < rem; ++k) e += vf[k] * uf[k];
    }
  }
  const float tj2 = block_reduce_sum(j2);
  const float te  = block_reduce_sum(e);
  if (threadIdx.x == 0) {
    atomicAdd(acc + 0, tj2);
    if (act) atomicAdd(acc + 1, te);
  }
}

// ---------------------------------------------------------------------------
// Token transpose: tokT[j][n] = X[n][j]
// ---------------------------------------------------------------------------
__global__ __launch_bounds__(256) void kern_tokT(
    const int* __restrict__ X, int* __restrict__ tokT) {
  const int idx = blockIdx.x * 256 + threadIdx.x;
  if (idx < LL * MM) {
    const int j = idx / MM;
    const int n = idx - j * MM;
    tokT[idx] = X[n * LL + j];
  }
}

// ---------------------------------------------------------------------------
// Phase 1: partial logits. Grid (NS, 2, 13): block = (site i, 512-seq chunk,
// 16-wide j-tile). One staging round, register partial logits (float2 pairs
// -> v_pk_add), 21 coalesced atomicAdds into logits[iIdx][a][n].
// ---------------------------------------------------------------------------
__global__ __launch_bounds__(512, 8) void kern_logz_p1(
    const float* __restrict__ J, const int* __restrict__ tokT,
    float* __restrict__ logits) {
  __shared__ float ldsJ[LDSJ_FLOATS];  // 29568 B
  const int i  = START + blockIdx.x;
  const int j0 = blockIdx.z * TJ;
  if (j0 >= i) return;                 // block-uniform, before any barrier
  const int t    = threadIdx.x;
  const int n    = blockIdx.y * 512 + t;
  const int tj   = min(TJ, i - j0);
  const int tj21 = tj * QQ;

  // Stage J[i,:,j0:j0+tj,:] as stride-22 [r=(jl*21+b)][a] rows.
  // Flat loop: idx -> a = idx/336 (const div), rem = jl*21+b (coalesced src).
  const float* Ji = J + (size_t)i * (QQ * LL * QQ) + j0 * QQ;
  for (int idx = t; idx < TJ * QQ * QQ; idx += 512) {
    const int a   = idx / (TJ * QQ);
    const int rem = idx - a * (TJ * QQ);
    if (rem < tj21) ldsJ[rem * RSTRIDE + a] = Ji[a * (LL * QQ) + rem];
  }
  __syncthreads();

  float2 lg2[10];
  #pragma unroll
  for (int k = 0; k < 10; ++k) lg2[k] = make_float2(0.0f, 0.0f);
  float lg20 = 0.0f;

  for (int jl = 0; jl < tj; ++jl) {
    const int b = tokT[(j0 + jl) * MM + n];
    const int r = (jl * QQ + b) * RSTRIDE;
    const float2* row2 = (const float2*)&ldsJ[r];   // 88B row stride -> 8B aligned
    #pragma unroll
    for (int k = 0; k < 10; ++k) {
      const float2 v = row2[k];
      lg2[k].x += v.x;
      lg2[k].y += v.y;
    }
    lg20 += ldsJ[r + 20];
  }

  float* dst = logits + (size_t)blockIdx.x * QQ * MM + n;
  #pragma unroll
  for (int k = 0; k < 10; ++k) {
    atomicAdd(dst + (2 * k) * MM, lg2[k].x);
    atomicAdd(dst + (2 * k + 1) * MM, lg2[k].y);
  }
  atomicAdd(dst + 20 * MM, lg20);
}

// ---------------------------------------------------------------------------
// Phase 2: logsumexp over a, weighted sum. Grid (NS, 16) x 64: one wave per
// (site, 64-seq chunk) -> 1072 small blocks for latency hiding.
// ---------------------------------------------------------------------------
__global__ __launch_bounds__(64) void kern_logz_p2(
    const float* __restrict__ logits, const float* __restrict__ h,
    const float* __restrict__ w, float* __restrict__ acc) {
  const int iI = blockIdx.x;
  const int i  = START + iI;
  const int n  = blockIdx.y * 64 + threadIdx.x;
  const float* hi  = h + i * QQ;
  const float* src = logits + (size_t)iI * QQ * MM + n;
  float lg[QQ];
  float mx = -3.0e38f;
  #pragma unroll
  for (int a = 0; a < QQ; ++a) {
    lg[a] = src[a * MM] + hi[a];
    mx = fmaxf(mx, lg[a]);
  }
  float s = 0.0f;
  #pragma unroll
  for (int a = 0; a < QQ; ++a) s += expf(lg[a] - mx);
  float v = w[n] * (mx + logf(s));
  #pragma unroll
  for (int off = 32; off > 0; off >>= 1) v += __shfl_down(v, off, 64);
  if (threadIdx.x == 0) atomicAdd(acc + 2, v);
}

// ---------------------------------------------------------------------------
// Fallback monolithic logz (only if ws too small for the slab).
// ---------------------------------------------------------------------------
#define LDSJ_MONO (32 * QQ * RSTRIDE)
__global__ __launch_bounds__(256) void kern_logz_mono(
    const float* __restrict__ J, const int* __restrict__ Xtok,
    const float* __restrict__ h, const float* __restrict__ w,
    float* __restrict__ acc) {
  __shared__ float ldsJ[LDSJ_MONO];
  const int i = START + blockIdx.x;
  const int t = threadIdx.x;
  const int n = blockIdx.y * 256 + t;
  float lg[QQ];
  #pragma unroll
  for (int a = 0; a < QQ; ++a) lg[a] = 0.0f;
  const float* Ji = J + (size_t)i * (QQ * LL * QQ);
  for (int j0 = 0; j0 < i; j0 += 32) {
    const int tj  = min(32, i - j0);
    const int cnt = tj * QQ;
    __syncthreads();
    for (int a = 0; a < QQ; ++a) {
      const float* src = Ji + a * (LL * QQ) + j0 * QQ;
      for (int idx = t; idx < cnt; idx += 256) {
        ldsJ[idx * RSTRIDE + a] = src[idx];
      }
    }
    __syncthreads();
    for (int jl = 0; jl < tj; ++jl) {
      const int b = Xtok[n * LL + (j0 + jl)];
      const float* row = &ldsJ[(jl * QQ + b) * RSTRIDE];
      #pragma unroll
      for (int a = 0; a < QQ; ++a) lg[a] += row[a];
    }
  }
  const float* hi = h + i * QQ;
  float mx = -3.0e38f;
  #pragma unroll
  for (int a = 0; a < QQ; ++a) { lg[a] += hi[a]; mx = fmaxf(mx, lg[a]); }
  float s = 0.0f;
  #pragma unroll
  for (int a = 0; a < QQ; ++a) s += expf(lg[a] - mx);
  const float contrib = w[n] * (mx + logf(s));
  const float tot = block_reduce_sum(contrib);
  if (t == 0) atomicAdd(acc + 2, tot);
}

// ---------------------------------------------------------------------------
// Final combine: h-side terms + weight normalization.
// ---------------------------------------------------------------------------
__global__ __launch_bounds__(256) void kern_final(
    const float* __restrict__ h, const float* __restrict__ fi,
    const float* __restrict__ w, const float* __restrict__ acc,
    float* __restrict__ out) {
  const int t = threadIdx.x;
  float hs = 0.0f, eh = 0.0f, ws = 0.0f;
  for (int idx = t; idx < LL * QQ; idx += 256) {
    const float hv = h[idx];
    hs += hv * hv;
    if (idx >= START * QQ) eh += fi[idx] * hv;
  }
  for (int idx = t; idx < MM; idx += 256) ws += w[idx];
  const float ths = block_reduce_sum(hs);
  const float teh = block_reduce_sum(eh);
  const float tws = block_reduce_sum(ws);
  if (t == 0) {
    const float energy = teh + acc[1];
    const float nll = acc[2] / tws - energy;
    out[0] = nll + RGH * ths + RGJ * acc[0];
    out[1] = nll;
  }
}

extern "C" void kernel_launch(void* const* d_in, const int* in_sizes, int n_in,
                              void* d_out, int out_size, void* d_ws, size_t ws_size,
                              hipStream_t stream) {
  const int*   Xtok = (const int*)  d_in[0];
  const float* wts  = (const float*)d_in[1];
  const float* fi   = (const float*)d_in[2];
  const float* fij  = (const float*)d_in[3];
  const float* h    = (const float*)d_in[4];
  const float* J    = (const float*)d_in[5];
  float* out    = (float*)d_out;
  float* acc    = (float*)d_ws;
  float* logits = (float*)((char*)d_ws + LOGITS_OFF);
  int*   tokT   = (int*)  ((char*)d_ws + TOKT_OFF);

  if (ws_size >= WS_NEED) {
    hipMemsetAsync(d_ws, 0, TOKT_OFF, stream);  // zero acc + logits slab
    kern_tokT<<<(LL * MM + 255) / 256, 256, 0, stream>>>(Xtok, tokT);
    kern_jsum<<<dim3(LL, QQ), 256, 0, stream>>>(J, fij, acc);
    kern_logz_p1<<<dim3(NS, 2, 13), 512, 0, stream>>>(J, tokT, logits);
    kern_logz_p2<<<dim3(NS, 16), 64, 0, stream>>>(logits, h, wts, acc);
    kern_final<<<1, 256, 0, stream>>>(h, fi, wts, acc, out);
  } else {
    hipMemsetAsync(d_ws, 0, 256, stream);
    kern_jsum<<<dim3(LL, QQ), 256, 0, stream>>>(J, fij, acc);
    kern_logz_mono<<<dim3(NS, 4), 256, 0, stream>>>(J, Xtok, h, wts, acc);
    kern_final<<<1, 256, 0, stream>>>(h, fi, wts, acc, out);
  }
}

// Round 4
// 286.896 us; speedup vs baseline: 1.0381x; 1.0381x over previous
//
#include <hip/hip_runtime.h>
#include <cstdint>

// Problem constants (from the reference)
#define LL    200
#define QQ    21
#define MM    1024
#define START 133        // 2*L//3
#define NS    67         // L - START
#define RGH   0.01f
#define RGJ   0.01f

// ws layout:
//   [0,256)            : acc[0]=sum(J^2), acc[1]=sum(J*fij), acc[2]=sum w*logZ
//   [256, +LL*MM*4)    : tokT (transposed tokens, [j][n])
#define TOKT_OFF 256
#define WS_NEED (TOKT_OFF + (size_t)LL * MM * 4)

// LDS row stride 22 floats (88 B): bank-start = 22r mod 32 -> 16 distinct even
// starts, max 2-way start aliasing; rows 8B-aligned -> ds_read_b64 legal.
#define RSTRIDE 22
#define TJ 32
#define LDSJ_FLOATS (TJ * QQ * RSTRIDE)   // 14784 floats = 59136 B

__device__ __forceinline__ float block_reduce_sum(float v) {
  // blockDim.x == 256 (4 waves) assumed
  __shared__ float sm[4];
  #pragma unroll
  for (int off = 32; off > 0; off >>= 1) v += __shfl_down(v, off, 64);
  const int lane = threadIdx.x & 63;
  const int wv   = threadIdx.x >> 6;
  __syncthreads();
  if (lane == 0) sm[wv] = v;
  __syncthreads();
  float r = 0.0f;
  if (threadIdx.x == 0) r = sm[0] + sm[1] + sm[2] + sm[3];
  return r;  // valid in thread 0 only
}

// ---------------------------------------------------------------------------
// sum(J^2) over all of J; sum(J*fij) over {i>=START, j<i}.
// Grid (LL, 4) x 256: block = (i-slice, quarter). Outer loop over a keeps the
// per-row prefix mask (pos < i*21) block-uniform; ~22 independent float4
// loads per thread for MLP. 1600 total atomics.
// ---------------------------------------------------------------------------
__global__ __launch_bounds__(256) void kern_jsum(
    const float* __restrict__ J, const float* __restrict__ fij,
    float* __restrict__ acc) {
  const int i = blockIdx.x;
  const size_t rb = (size_t)i * (QQ * LL * QQ);
  const bool act = (i >= START);
  const int lim  = act ? i * QQ : 0;   // floats in each row with j<i
  const int lim4 = lim >> 2;
  const int rem  = lim & 3;
  float j2 = 0.0f, e = 0.0f;
  const int f0 = blockIdx.y * 256 + threadIdx.x;
  for (int a = 0; a < QQ; ++a) {
    const float4* __restrict__ J4 = (const float4*)(J + rb + a * (LL * QQ));
    const float4* __restrict__ F4 = (const float4*)(fij + rb + a * (LL * QQ));
    for (int f = f0; f < (LL * QQ / 4); f += 1024) {
      const float4 v = J4[f];
      j2 += v.x * v.x + v.y * v.y + v.z * v.z + v.w * v.w;
      if (f < lim4) {
        const float4 u = F4[f];
        e += v.x * u.x + v.y * u.y + v.z * u.z + v.w * u.w;
      } else if (f == lim4 && rem) {
        const float* vf = (const float*)&v;
        const float* uf = (const float*)(F4 + f);
        for (int k = 0; k < rem; ++k) e += vf[k] * uf[k];
      }
    }
  }
  const float tj2 = block_reduce_sum(j2);
  const float te  = block_reduce_sum(e);
  if (threadIdx.x == 0) {
    atomicAdd(acc + 0, tj2);
    if (act) atomicAdd(acc + 1, te);
  }
}

// ---------------------------------------------------------------------------
// Token transpose: tokT[j][n] = X[n][j]
// ---------------------------------------------------------------------------
__global__ __launch_bounds__(256) void kern_tokT(
    const int* __restrict__ X, int* __restrict__ tokT) {
  const int idx = blockIdx.x * 256 + threadIdx.x;
  if (idx < LL * MM) {
    const int j = idx / MM;
    const int n = idx - j * MM;
    tokT[idx] = X[n * LL + j];
  }
}

// ---------------------------------------------------------------------------
// Gather one staged tile: tj rows, byte-offsets pre-multiplied in boff[].
// Fully unrolled so boff[] stays const-indexed (no scratch); uniform break.
// ---------------------------------------------------------------------------
__device__ __forceinline__ void gather_tile(
    const float* __restrict__ ldsJ, const int* __restrict__ boff, int tj,
    float2 lg2[10], float& lg20) {
  #pragma unroll
  for (int jl = 0; jl < TJ; ++jl) {
    if (jl >= tj) break;               // block-uniform
    // row float-offset = jl*QQ*RSTRIDE + b*RSTRIDE; b*RSTRIDE is in boff[jl],
    // jl*462 folds into the ds_read offset: field (max 1848*31+80 < 64K).
    const float* row = ldsJ + jl * (QQ * RSTRIDE) + boff[jl];
    const float2* row2 = (const float2*)row;
    #pragma unroll
    for (int k = 0; k < 10; ++k) {
      const float2 v = row2[k];
      lg2[k].x += v.x;
      lg2[k].y += v.y;
    }
    lg20 += row[20];
  }
}

// ---------------------------------------------------------------------------
// Fused logits+logsumexp. Grid (NS, 4) x 256: block = (site i, 256 seqs),
// ALL j inside the block -> no cross-block reduction, no logits slab.
// Per 32-j tile: stage J[i,:,tile,:] to LDS as stride-22 [j*21+b][a] rows;
// prefetch the 32 tokens as register byte-offsets (coalesced); fully
// unrolled independent ds_read_b64 gather (ILP-driven latency hiding).
// ---------------------------------------------------------------------------
__global__ __launch_bounds__(256) void kern_logz(
    const float* __restrict__ J, const int* __restrict__ tokT,
    const int* __restrict__ Xtok, const int useT,
    const float* __restrict__ h, const float* __restrict__ w,
    float* __restrict__ acc) {
  __shared__ float ldsJ[LDSJ_FLOATS];  // 59136 B
  const int i = START + blockIdx.x;
  const int t = threadIdx.x;
  const int n = blockIdx.y * 256 + t;

  float2 lg2[10];
  #pragma unroll
  for (int k = 0; k < 10; ++k) lg2[k] = make_float2(0.0f, 0.0f);
  float lg20 = 0.0f;

  const float* Ji = J + (size_t)i * (QQ * LL * QQ);
  const int nfull = i >> 5;        // full 32-j tiles
  const int remtj = i & 31;        // trailing partial tile

  int boff[TJ];                    // b*RSTRIDE per row of current tile

  for (int s = 0; s < nfull; ++s) {
    const int j0 = s * TJ;
    // Token prefetch: TJ independent coalesced loads -> one waitcnt.
    #pragma unroll
    for (int k = 0; k < TJ; ++k) {
      const int b = useT ? tokT[(j0 + k) * MM + n] : Xtok[n * LL + (j0 + k)];
      boff[k] = b * RSTRIDE;
    }
    __syncthreads();               // previous gather done before overwrite
    // Stage: full tile, flat index, compile-time divisor (168 float4 / row).
    for (int idx = t; idx < QQ * 168; idx += 256) {
      const int a  = idx / 168;
      const int g  = idx - a * 168;
      const int r0 = 4 * g;
      const float4 v = *(const float4*)(Ji + a * (LL * QQ) + j0 * QQ + r0);
      ldsJ[(r0 + 0) * RSTRIDE + a] = v.x;
      ldsJ[(r0 + 1) * RSTRIDE + a] = v.y;
      ldsJ[(r0 + 2) * RSTRIDE + a] = v.z;
      ldsJ[(r0 + 3) * RSTRIDE + a] = v.w;
    }
    __syncthreads();
    gather_tile(ldsJ, boff, TJ, lg2, lg20);
  }

  if (remtj) {
    const int j0 = nfull * TJ;
    #pragma unroll
    for (int k = 0; k < TJ; ++k) {
      int b = 0;
      if (k < remtj)
        b = useT ? tokT[(j0 + k) * MM + n] : Xtok[n * LL + (j0 + k)];
      boff[k] = b * RSTRIDE;
    }
    __syncthreads();
    const int tj21 = remtj * QQ;
    const int cnt4 = (tj21 + 3) >> 2;
    for (int a = 0; a < QQ; ++a) {
      const float* src = Ji + a * (LL * QQ) + j0 * QQ;
      for (int g = t; g < cnt4; g += 256) {
        const int r0 = 4 * g;
        // last float4 may read <=3 floats past the tile; stays inside row a
        // of slice i (i*21+2 <= 4182 < 4200), so in-bounds.
        const float4 v = *(const float4*)(src + r0);
        ldsJ[r0 * RSTRIDE + a] = v.x;
        if (r0 + 1 < tj21) ldsJ[(r0 + 1) * RSTRIDE + a] = v.y;
        if (r0 + 2 < tj21) ldsJ[(r0 + 2) * RSTRIDE + a] = v.z;
        if (r0 + 3 < tj21) ldsJ[(r0 + 3) * RSTRIDE + a] = v.w;
      }
    }
    __syncthreads();
    gather_tile(ldsJ, boff, remtj, lg2, lg20);
  }

  // Epilogue: + h, logsumexp over the 21 states, weighted block sum.
  const float* hi = h + i * QQ;
  float lg[QQ];
  #pragma unroll
  for (int k = 0; k < 10; ++k) {
    lg[2 * k]     = lg2[k].x + hi[2 * k];
    lg[2 * k + 1] = lg2[k].y + hi[2 * k + 1];
  }
  lg[20] = lg20 + hi[20];
  float mx = -3.0e38f;
  #pragma unroll
  for (int a = 0; a < QQ; ++a) mx = fmaxf(mx, lg[a]);
  float sum = 0.0f;
  #pragma unroll
  for (int a = 0; a < QQ; ++a) sum += expf(lg[a] - mx);
  const float contrib = w[n] * (mx + logf(sum));
  const float tot = block_reduce_sum(contrib);
  if (t == 0) atomicAdd(acc + 2, tot);
}

// ---------------------------------------------------------------------------
// Final combine: h-side terms + weight normalization.
// ---------------------------------------------------------------------------
__global__ __launch_bounds__(256) void kern_final(
    const float* __restrict__ h, const float* __restrict__ fi,
    const float* __restrict__ w, const float* __restrict__ acc,
    float* __restrict__ out) {
  const int t = threadIdx.x;
  float hs = 0.0f, eh = 0.0f, ws = 0.0f;
  for (int idx = t; idx < LL * QQ; idx += 256) {
    const float hv = h[idx];
    hs += hv * hv;
    if (idx >= START * QQ) eh += fi[idx] * hv;
  }
  for (int idx = t; idx < MM; idx += 256) ws += w[idx];
  const float ths = block_reduce_sum(hs);
  const float teh = block_reduce_sum(eh);
  const float tws = block_reduce_sum(ws);
  if (t == 0) {
    const float energy = teh + acc[1];
    const float nll = acc[2] / tws - energy;
    out[0] = nll + RGH * ths + RGJ * acc[0];
    out[1] = nll;
  }
}

extern "C" void kernel_launch(void* const* d_in, const int* in_sizes, int n_in,
                              void* d_out, int out_size, void* d_ws, size_t ws_size,
                              hipStream_t stream) {
  const int*   Xtok = (const int*)  d_in[0];
  const float* wts  = (const float*)d_in[1];
  const float* fi   = (const float*)d_in[2];
  const float* fij  = (const float*)d_in[3];
  const float* h    = (const float*)d_in[4];
  const float* J    = (const float*)d_in[5];
  float* out  = (float*)d_out;
  float* acc  = (float*)d_ws;
  int*   tokT = (int*)((char*)d_ws + TOKT_OFF);
  const int useT = (ws_size >= WS_NEED) ? 1 : 0;

  hipMemsetAsync(d_ws, 0, 256, stream);  // zero the 3 accumulators
  if (useT) {
    kern_tokT<<<(LL * MM + 255) / 256, 256, 0, stream>>>(Xtok, tokT);
  }
  kern_jsum<<<dim3(LL, 4), 256, 0, stream>>>(J, fij, acc);
  kern_logz<<<dim3(NS, 4), 256, 0, stream>>>(J, tokT, Xtok, useT, h, wts, acc);
  kern_final<<<1, 256, 0, stream>>>(h, fi, wts, acc, out);
}